// Round 17
// baseline (97.097 us; speedup 1.0000x reference)
//
#include <hip/hip_runtime.h>

#define E_   1024
#define H_   16
#define DK_  64
#define FFN_ 4096
#define NQ_  8
#define B_   2
#define T_   2048
#define QBLK 128
#define KVBLK 64
#define NT_  (T_ / KVBLK)

#define NPART 256
#define ROWS_PER_PART (FFN_ / NPART)   // 16

typedef __attribute__((ext_vector_type(8))) __bf16 bf16x8;
typedef __attribute__((ext_vector_type(4))) float f32x4;
typedef __attribute__((ext_vector_type(16))) float f32x16;

__device__ __forceinline__ __bf16 tobf(float f) { return (__bf16)f; }

__device__ __forceinline__ unsigned pk2(float a, float b) {
  union { __bf16 h; unsigned short u; } ua, ub;
  ua.h = (__bf16)a; ub.h = (__bf16)b;
  return (unsigned)ua.u | ((unsigned)ub.u << 16);
}

// ---------------------------------------------------------------------------
// Kernel 0: tiled convert+transpose: x -> xbf [b][t][e] AND xbfT [b][h][d][t]
// ---------------------------------------------------------------------------
__global__ __launch_bounds__(256)
void cvt_kernel(const float* __restrict__ x, __bf16* __restrict__ xbf,
                __bf16* __restrict__ xbfT) {
  __shared__ __bf16 tile[64][66];
  const int tid = threadIdx.x;
  const int bid = blockIdx.x;
  const int h  = bid & 15;
  const int tt = (bid >> 4) & 31;
  const int b  = bid >> 9;
  const float* src = x + ((size_t)(b * T_ + tt * 64)) * E_ + h * 64;

#pragma unroll
  for (int u = 0; u < 2; ++u) {
    const int idx = tid + 256 * u;
    const int r = idx >> 3;
    const int c = (idx & 7) * 8;
    float4 f0 = *reinterpret_cast<const float4*>(src + (size_t)r * E_ + c);
    float4 f1 = *reinterpret_cast<const float4*>(src + (size_t)r * E_ + c + 4);
    bf16x8 v;
    v[0] = tobf(f0.x); v[1] = tobf(f0.y); v[2] = tobf(f0.z); v[3] = tobf(f0.w);
    v[4] = tobf(f1.x); v[5] = tobf(f1.y); v[6] = tobf(f1.z); v[7] = tobf(f1.w);
    *reinterpret_cast<bf16x8*>(
        &xbf[((size_t)(b * T_ + tt * 64 + r)) * E_ + h * 64 + c]) = v;
#pragma unroll
    for (int j = 0; j < 8; ++j) tile[r][c + j] = v[j];
  }
  __syncthreads();
#pragma unroll
  for (int u = 0; u < 2; ++u) {
    const int idx = tid + 256 * u;
    const int d  = idx >> 3;
    const int tc = (idx & 7) * 8;
    bf16x8 v;
#pragma unroll
    for (int j = 0; j < 8; ++j) v[j] = tile[tc + j][d];
    *reinterpret_cast<bf16x8*>(
        &xbfT[((size_t)((b * H_ + h) * DK_ + d)) * T_ + tt * 64 + tc]) = v;
  }
}

// ---------------------------------------------------------------------------
// Kernel 1a/1b: constant FFN via split-K (unchanged).
// ---------------------------------------------------------------------------
__global__ __launch_bounds__(256)
void ffn_part_kernel(const float* __restrict__ q_out, const float* __restrict__ w1,
                     const float* __restrict__ b1, const float* __restrict__ w2,
                     float* __restrict__ part) {
  __shared__ float h[ROWS_PER_PART];
  const int tid = threadIdx.x;
  const int p = blockIdx.x;
  const int f0 = p * ROWS_PER_PART;
  if (tid < ROWS_PER_PART) {
    const int f = f0 + tid;
    float a = b1[f];
#pragma unroll
    for (int n = 0; n < NQ_; ++n) a += q_out[n] * w1[n * FFN_ + f];
    h[tid] = fmaxf(a, 0.f);
  }
  __syncthreads();
  float4 acc = {0.f, 0.f, 0.f, 0.f};
#pragma unroll
  for (int j = 0; j < ROWS_PER_PART; ++j) {
    const float hf = h[j];
    float4 w = reinterpret_cast<const float4*>(w2 + (size_t)(f0 + j) * E_)[tid];
    acc.x += hf * w.x; acc.y += hf * w.y; acc.z += hf * w.z; acc.w += hf * w.w;
  }
  reinterpret_cast<float4*>(part + (size_t)p * E_)[tid] = acc;
}

__global__ __launch_bounds__(256)
void ffn_reduce_kernel(const float* __restrict__ part, const float* __restrict__ b2,
                       float* __restrict__ ffn_c) {
  const int e = blockIdx.x * 256 + threadIdx.x;
  float a = b2[e];
  for (int r = 0; r < NPART; ++r) a += part[(size_t)r * E_ + e];
  ffn_c[e] = a;
}

// ---------------------------------------------------------------------------
// Kernel 2: flash attention on 32x32x16 MFMA.  Swapped QK^T (lane=qrow in S),
// in-register P via cvt_pk + shfl_xor(32) (NO P LDS), double-buffered Kt/VtF,
// one barrier/tile, T14 issue-early/write-late.  grid=(T/128, B*H) x 256 thr.
// ---------------------------------------------------------------------------
#define PV_STEP(KS, DARR, OARR)                                                \
  do {                                                                         \
    const int mA = 2 * ((KS) & 1), mB = mA + 1;                                \
    union { unsigned u[4]; bf16x8 v; } pa;                                     \
    pa.u[0] = hi ? OARR[mB][0] : DARR[mA][0];                                  \
    pa.u[1] = hi ? OARR[mB][1] : DARR[mA][1];                                  \
    pa.u[2] = hi ? DARR[mB][0] : OARR[mA][0];                                  \
    pa.u[3] = hi ? DARR[mB][1] : OARR[mA][1];                                  \
    bf16x8 vb0 = *reinterpret_cast<const bf16x8*>(                             \
        Vtc + rowA + (((32 * (KS) + 16 * hi) ^ rxA)));                         \
    bf16x8 vb1 = *reinterpret_cast<const bf16x8*>(                             \
        Vtc + rowB + (((32 * (KS) + 16 * hi) ^ rxB)));                         \
    acc0 = __builtin_amdgcn_mfma_f32_32x32x16_bf16(pa.v, vb0, acc0, 0, 0, 0);  \
    acc1 = __builtin_amdgcn_mfma_f32_32x32x16_bf16(pa.v, vb1, acc1, 0, 0, 0);  \
  } while (0)

__global__ __launch_bounds__(256)
void attn_kernel(const __bf16* __restrict__ xbf, const __bf16* __restrict__ xbfT,
                 float* __restrict__ out) {
  __shared__ __bf16 Kt[2][KVBLK][DK_ + 8];   // [buf][key][d]
  __shared__ __bf16 VtF[2][DK_ * KVBLK];     // [buf][d][key], byte^=(rot(d)<<4)

  const int tid  = threadIdx.x;
  const int wave = tid >> 6;
  const int lane = tid & 63;
  const int l32  = lane & 31;
  const int hi   = lane >> 5;

  const int bh = blockIdx.y;
  const int b  = bh >> 4;
  const int h  = bh & 15;
  const int qbase = blockIdx.x * QBLK;
  const __bf16* xb = xbf + (size_t)b * T_ * E_ + h * DK_;

  // Q B-frags: qb[ks] = Q[qrow=l32][16ks+8hi .. +7] * 0.125 (exact)
  bf16x8 qb[4];
  {
    const __bf16 sc = (__bf16)0.125f;
    const __bf16* qrow = xb + (size_t)(qbase + wave * 32 + l32) * E_;
#pragma unroll
    for (int ks = 0; ks < 4; ++ks) {
      bf16x8 v = *reinterpret_cast<const bf16x8*>(qrow + 16 * ks + 8 * hi);
#pragma unroll
      for (int j = 0; j < 8; ++j) v[j] *= sc;
      qb[ks] = v;
    }
  }

  f32x16 acc0, acc1;
#pragma unroll
  for (int j = 0; j < 16; ++j) { acc0[j] = 0.f; acc1[j] = 0.f; }
  float lg = 0.f;

  // VtF read constants: rows d=l32 (ob0) and 32+l32 (ob1)
  const int rotA = (l32 & 7) ^ ((l32 >> 3) & 7);
  const int rotB = (l32 & 7) ^ ((4 + (l32 >> 3)) & 7);
  const int rowA = l32 * 128, rxA = rotA << 4;
  const int rowB = (32 + l32) * 128, rxB = rotB << 4;

  // staging: K rows 2kp,2kp+1 (d-cols ds0..+7) from xbf; V rows dv,dv+32 from xbfT
  const int kp  = tid >> 3;             // 0..31
  const int ds0 = (tid & 7) * 8;
  const __bf16* kbase = xb + (size_t)(2 * kp) * E_ + ds0;
  const int dv = tid >> 3;
  const int kv = (tid & 7) * 8;
  const __bf16* vbase = xbfT + ((size_t)(bh * DK_ + dv)) * T_ + kv;
  const int srotA = (dv & 7) ^ ((dv >> 3) & 7);
  const int dvB = dv + 32;
  const int srotB = (dvB & 7) ^ ((dvB >> 3) & 7);
  const int vbyteA = dv * 128 + ((kv * 2) ^ (srotA << 4));
  const int vbyteB = dvB * 128 + ((kv * 2) ^ (srotB << 4));

  // ---- prologue: stage tile 0 into buf 0 ----
  {
    uint4 k0 = *reinterpret_cast<const uint4*>(kbase);
    uint4 k1 = *reinterpret_cast<const uint4*>(kbase + E_);
    uint4 v0 = *reinterpret_cast<const uint4*>(vbase);
    uint4 v1 = *reinterpret_cast<const uint4*>(vbase + (size_t)32 * T_);
    *reinterpret_cast<uint4*>(&Kt[0][2 * kp][ds0])     = k0;
    *reinterpret_cast<uint4*>(&Kt[0][2 * kp + 1][ds0]) = k1;
    char* vb = reinterpret_cast<char*>(&VtF[0][0]);
    *reinterpret_cast<uint4*>(vb + vbyteA) = v0;
    *reinterpret_cast<uint4*>(vb + vbyteB) = v1;
  }
  __syncthreads();

  for (int t = 0; t < NT_; ++t) {
    const int cur = t & 1;
    const __bf16* Ktc = &Kt[cur][0][0];
    const char*   Vtc = reinterpret_cast<const char*>(&VtF[cur][0]);

    // ---- T14: issue next tile's global loads FIRST ----
    uint4 nk0, nk1, nv0, nv1;
    const bool have_next = (t + 1 < NT_);
    if (have_next) {
      const __bf16* nk = kbase + (size_t)(t + 1) * KVBLK * E_;
      const __bf16* nv = vbase + (size_t)(t + 1) * KVBLK;
      nk0 = *reinterpret_cast<const uint4*>(nk);
      nk1 = *reinterpret_cast<const uint4*>(nk + E_);
      nv0 = *reinterpret_cast<const uint4*>(nv);
      nv1 = *reinterpret_cast<const uint4*>(nv + (size_t)32 * T_);
    }

    // ---- S^T = K (Q/8)^T : s0 = keys 0..31, s1 = keys 32..63 ----
    f32x16 s0, s1;
#pragma unroll
    for (int j = 0; j < 16; ++j) { s0[j] = 0.f; s1[j] = 0.f; }
    __builtin_amdgcn_s_setprio(1);
#pragma unroll
    for (int ks = 0; ks < 4; ++ks) {
      bf16x8 ka0 = *reinterpret_cast<const bf16x8*>(
          Ktc + (size_t)l32 * (DK_ + 8) + 16 * ks + 8 * hi);
      bf16x8 ka1 = *reinterpret_cast<const bf16x8*>(
          Ktc + (size_t)(32 + l32) * (DK_ + 8) + 16 * ks + 8 * hi);
      s0 = __builtin_amdgcn_mfma_f32_32x32x16_bf16(ka0, qb[ks], s0, 0, 0, 0);
      s1 = __builtin_amdgcn_mfma_f32_32x32x16_bf16(ka1, qb[ks], s1, 0, 0, 0);
    }
    __builtin_amdgcn_s_setprio(0);

    // ---- static-max softmax: exp + lane-local l + pack to bf16 pairs ----
    unsigned dA_[4][2], dB_[4][2], oA_[4][2], oB_[4][2];
#pragma unroll
    for (int m = 0; m < 4; ++m) {
      float a0 = __expf(s0[4 * m + 0]), a1 = __expf(s0[4 * m + 1]);
      float a2 = __expf(s0[4 * m + 2]), a3 = __expf(s0[4 * m + 3]);
      lg += (a0 + a1) + (a2 + a3);
      dA_[m][0] = pk2(a0, a1); dA_[m][1] = pk2(a2, a3);
      float b0 = __expf(s1[4 * m + 0]), b1 = __expf(s1[4 * m + 1]);
      float b2 = __expf(s1[4 * m + 2]), b3 = __expf(s1[4 * m + 3]);
      lg += (b0 + b1) + (b2 + b3);
      dB_[m][0] = pk2(b0, b1); dB_[m][1] = pk2(b2, b3);
    }
    // ---- exchange halves (lane <-> lane+32), pure cross-lane, no LDS buf ----
#pragma unroll
    for (int m = 0; m < 4; ++m) {
      oA_[m][0] = (unsigned)__shfl_xor((int)dA_[m][0], 32);
      oA_[m][1] = (unsigned)__shfl_xor((int)dA_[m][1], 32);
      oB_[m][0] = (unsigned)__shfl_xor((int)dB_[m][0], 32);
      oB_[m][1] = (unsigned)__shfl_xor((int)dB_[m][1], 32);
    }

    // ---- O += P V ----
    __builtin_amdgcn_s_setprio(1);
    PV_STEP(0, dA_, oA_);
    PV_STEP(1, dA_, oA_);
    PV_STEP(2, dB_, oB_);
    PV_STEP(3, dB_, oB_);
    __builtin_amdgcn_s_setprio(0);

    // ---- T14 write-late: stage tile t+1 into buf cur^1 ----
    if (have_next) {
      const int nxt = cur ^ 1;
      *reinterpret_cast<uint4*>(&Kt[nxt][2 * kp][ds0])     = nk0;
      *reinterpret_cast<uint4*>(&Kt[nxt][2 * kp + 1][ds0]) = nk1;
      char* vb = reinterpret_cast<char*>(&VtF[nxt][0]);
      *reinterpret_cast<uint4*>(vb + vbyteA) = nv0;
      *reinterpret_cast<uint4*>(vb + vbyteB) = nv1;
    }
    __syncthreads();   // single barrier per tile (2-iteration separation)
  }

  // ---- epilogue: complete l across halves, write O/l ----
  lg += __shfl_xor(lg, 32);
#pragma unroll
  for (int r = 0; r < 16; ++r) {
    const int qw = (r & 3) + 8 * (r >> 2) + 4 * hi;   // q-row within wave's 32
    const float inv = 1.f / __shfl(lg, qw);
    const size_t q = (size_t)b * T_ + qbase + wave * 32 + qw;
    out[q * E_ + h * 64 + l32]      = acc0[r] * inv;
    out[q * E_ + h * 64 + 32 + l32] = acc1[r] * inv;
  }
}

// ---------------------------------------------------------------------------
// Kernel 3: out = LN2( LN1(x + attn) + ffn_c ), in-place on d_out.
// ---------------------------------------------------------------------------
__device__ __forceinline__ float block_sum(float v, float* redrow, int lane, int wave) {
#pragma unroll
  for (int off = 1; off < 64; off <<= 1) v += __shfl_xor(v, off);
  if (lane == 0) redrow[wave] = v;
  __syncthreads();
  return redrow[0] + redrow[1] + redrow[2] + redrow[3];
}

__global__ __launch_bounds__(256)
void ln_kernel(const float* __restrict__ x, const float* __restrict__ ffn_c,
               const float* __restrict__ g1, const float* __restrict__ be1,
               const float* __restrict__ g2, const float* __restrict__ be2,
               float* io) {
  __shared__ float red[4][4];
  const int row = blockIdx.x;
  const int tid = threadIdx.x;
  const int lane = tid & 63, wave = tid >> 6;
  const float* xr = x + (size_t)row * E_;
  float* ior = io + (size_t)row * E_;

  float4 xv = reinterpret_cast<const float4*>(xr)[tid];
  float4 av = reinterpret_cast<const float4*>(ior)[tid];
  float v[4] = {xv.x + av.x, xv.y + av.y, xv.z + av.z, xv.w + av.w};

  float mu1 = block_sum(v[0] + v[1] + v[2] + v[3], red[0], lane, wave) * (1.f / E_);
  float q1 = 0.f;
#pragma unroll
  for (int j = 0; j < 4; ++j) { float d = v[j] - mu1; q1 += d * d; }
  float var1 = block_sum(q1, red[1], lane, wave) * (1.f / E_);
  float rs1 = rsqrtf(var1 + 1e-5f);

  const int e0 = tid * 4;
  float y[4];
#pragma unroll
  for (int j = 0; j < 4; ++j)
    y[j] = (v[j] - mu1) * rs1 * g1[e0 + j] + be1[e0 + j] + ffn_c[e0 + j];

  float mu2 = block_sum(y[0] + y[1] + y[2] + y[3], red[2], lane, wave) * (1.f / E_);
  float q2 = 0.f;
#pragma unroll
  for (int j = 0; j < 4; ++j) { float d = y[j] - mu2; q2 += d * d; }
  float var2 = block_sum(q2, red[3], lane, wave) * (1.f / E_);
  float rs2 = rsqrtf(var2 + 1e-5f);

  float4 o;
  o.x = (y[0] - mu2) * rs2 * g2[e0 + 0] + be2[e0 + 0];
  o.y = (y[1] - mu2) * rs2 * g2[e0 + 1] + be2[e0 + 1];
  o.z = (y[2] - mu2) * rs2 * g2[e0 + 2] + be2[e0 + 2];
  o.w = (y[3] - mu2) * rs2 * g2[e0 + 3] + be2[e0 + 3];
  reinterpret_cast<float4*>(ior)[tid] = o;
}

// ---------------------------------------------------------------------------
extern "C" void kernel_launch(void* const* d_in, const int* in_sizes, int n_in,
                              void* d_out, int out_size, void* d_ws, size_t ws_size,
                              hipStream_t stream) {
  (void)in_sizes; (void)n_in; (void)out_size; (void)ws_size;
  const float* x     = (const float*)d_in[0];
  const float* q_out = (const float*)d_in[2];
  const float* w1    = (const float*)d_in[3];
  const float* b1    = (const float*)d_in[4];
  const float* w2    = (const float*)d_in[5];
  const float* b2    = (const float*)d_in[6];
  const float* g1    = (const float*)d_in[7];
  const float* be1   = (const float*)d_in[8];
  const float* g2    = (const float*)d_in[9];
  const float* be2   = (const float*)d_in[10];
  float* out   = (float*)d_out;

  float* ffn_c = (float*)d_ws;                               // E_ floats
  float* part  = ffn_c + E_;                                 // NPART*E_ floats
  __bf16* xbf  = (__bf16*)(part + (size_t)NPART * E_);       // B*T*E bf16
  __bf16* xbfT = xbf + (size_t)B_ * T_ * E_;                 // B*H*DK*T bf16

  cvt_kernel<<<B_ * (T_ / 64) * H_, 256, 0, stream>>>(x, xbf, xbfT);
  ffn_part_kernel<<<NPART, 256, 0, stream>>>(q_out, w1, b1, w2, part);
  ffn_reduce_kernel<<<E_ / 256, 256, 0, stream>>>(part, b2, ffn_c);
  dim3 ag(T_ / QBLK, B_ * H_);
  attn_kernel<<<ag, 256, 0, stream>>>(xbf, xbfT, out);
  ln_kernel<<<B_ * T_, 256, 0, stream>>>(x, ffn_c, g1, be1, g2, be2, out);
}